// Round 1
// baseline (413.754 us; speedup 1.0000x reference)
//
#include <hip/hip_runtime.h>
#include <hip/hip_bf16.h>

// Problem constants
#define NB 4
#define NC 256
#define ND 32
#define WH 1024          // W*H
#define DWH 32768        // D*W*H
#define KTOT 1024        // 4 modalities * 256 channels

typedef __attribute__((ext_vector_type(8))) short short8;
typedef __attribute__((ext_vector_type(4))) float f32x4;

static __device__ __forceinline__ unsigned short f32_to_bf16(float f) {
    unsigned u = __builtin_bit_cast(unsigned, f);
    u = u + 0x7fff + ((u >> 16) & 1);   // round-to-nearest-even
    return (unsigned short)(u >> 16);
}

// ---------------------------------------------------------------------------
// Kernel 1: adaptive_avg_pool3d(x,(D,1,1)) == mean over W,H -> pooled[b][c][m][d]
// One block per (b,c,m). 256 threads = 4 waves; wave w handles rows d=w,w+4,...
// ---------------------------------------------------------------------------
__global__ __launch_bounds__(256) void pool_kernel(
    const float* __restrict__ i0, const float* __restrict__ i1,
    const float* __restrict__ i2, const float* __restrict__ i3,
    float* __restrict__ pooled)
{
    int bid = blockIdx.x;            // (b*NC + c)*4 + m
    int m   = bid & 3;
    int bc  = bid >> 2;              // b*NC + c
    const float* src = (m == 0 ? i0 : m == 1 ? i1 : m == 2 ? i2 : i3)
                       + (size_t)bc * DWH;
    int t = threadIdx.x;
    int wave = t >> 6, lane = t & 63;

    for (int d = wave; d < ND; d += 4) {
        const float4* row = (const float4*)(src + (size_t)d * WH);
        float s = 0.f;
        #pragma unroll
        for (int j = 0; j < 4; ++j) {
            float4 v = row[lane + 64 * j];
            s += v.x + v.y + v.z + v.w;
        }
        #pragma unroll
        for (int off = 32; off; off >>= 1) s += __shfl_down(s, off, 64);
        if (lane == 0) pooled[bc * 128 + m * 32 + d] = s * (1.0f / 1024.0f);
    }
}

// ---------------------------------------------------------------------------
// Kernel 2: attention weights + effective GEMM A-matrix + effective bias.
// One 64-thread block per (b,c).
//   q[e]  = sum_d pooled[b,c,0,d]*Wq[e,d] + bq[e]
//   k[m,e]= sum_d pooled[b,c,m,d]*Wk[e,d] + bk[e]
//   a     = softmax( (q . k_m)/sqrt(32) )
//   Amat[b][o=c][m*256+cin] = bf16( a[m] * Wc[m][o][cin] )
//   beff[b][o] = sum_m a[m]*bc[m][o]
// ---------------------------------------------------------------------------
__global__ __launch_bounds__(64) void attn_kernel(
    const float* __restrict__ pooled,
    const float* __restrict__ Wq, const float* __restrict__ bq,
    const float* __restrict__ Wk, const float* __restrict__ bk,
    const float* __restrict__ Wc, const float* __restrict__ bcv,
    unsigned short* __restrict__ Amat, float* __restrict__ beff)
{
    int bc_idx = blockIdx.x;             // b*NC + c
    int lane = threadIdx.x;
    int e = lane & 31;
    const float* P = pooled + bc_idx * 128;

    float q = 0.f, kv[4] = {0.f, 0.f, 0.f, 0.f};
    for (int d = 0; d < 32; ++d) {
        float pq = P[d];                 // pooled m=0 (broadcast)
        float wq = Wq[e * 32 + d], wk = Wk[e * 32 + d];
        q += pq * wq;
        #pragma unroll
        for (int m = 0; m < 4; ++m) kv[m] += P[m * 32 + d] * wk;
    }
    q += bq[e];
    #pragma unroll
    for (int m = 0; m < 4; ++m) kv[m] += bk[e];

    float lg[4];
    #pragma unroll
    for (int m = 0; m < 4; ++m) {
        float p = q * kv[m];
        #pragma unroll
        for (int off = 16; off; off >>= 1) p += __shfl_xor(p, off, 32);
        lg[m] = p * 0.17677669529663687f;    // 1/sqrt(32)
    }
    float mx = fmaxf(fmaxf(lg[0], lg[1]), fmaxf(lg[2], lg[3]));
    float ex[4], s = 0.f;
    #pragma unroll
    for (int m = 0; m < 4; ++m) { ex[m] = __expf(lg[m] - mx); s += ex[m]; }
    float a[4];
    #pragma unroll
    for (int m = 0; m < 4; ++m) a[m] = ex[m] / s;

    int c = bc_idx & 255;
    if (lane == 0) {
        float be = 0.f;
        #pragma unroll
        for (int m = 0; m < 4; ++m) be += a[m] * bcv[m * NC + c];
        beff[bc_idx] = be;
    }
    // Build effective A row: k = m*256 + cin
    unsigned short* Arow = Amat + (size_t)bc_idx * KTOT;
    #pragma unroll
    for (int j = 0; j < 16; ++j) {
        int k = j * 64 + lane;
        int m = k >> 8, cin = k & 255;
        float v = a[m] * Wc[(m * NC + c) * NC + cin];
        Arow[k] = f32_to_bf16(v);
    }
}

// ---------------------------------------------------------------------------
// Kernel 3: per-batch GEMM out[b][o][x] = sum_k Amat[b][o][k]*M[b][k][x] + beff
//   M=256 (o), N=32768 (x), K=1024. Tile 128x128, BK=64, 4 waves (2x2),
//   each wave 64x64 = 4x4 MFMA 16x16x32 bf16 fragments.
//   B operand (fp32 inputs) is converted to bf16 during reg-staging and
//   written K-contiguous (transposed) into LDS. Both LDS tiles XOR-swizzled:
//   16B-chunk index q -> q ^ (row&7), giving uniform bank use on
//   ds_read_b128 fragment reads (rows stride 128B otherwise = same bank).
// ---------------------------------------------------------------------------
#define BM 128
#define BN 128
#define BK 64

static __device__ __forceinline__ int swz(int row, int chunk) {
    // ushort units: row stride 64 ushorts (=128B), chunk = 8 ushorts (=16B)
    return row * 64 + ((chunk ^ (row & 7)) << 3);
}

__global__ __launch_bounds__(256, 2) void gemm_kernel(
    const float* __restrict__ i0, const float* __restrict__ i1,
    const float* __restrict__ i2, const float* __restrict__ i3,
    const unsigned short* __restrict__ Amat,
    const float* __restrict__ beff,
    float* __restrict__ out)
{
    __shared__ __align__(16) short As[BM * BK];   // [o][k] swizzled, 16KB
    __shared__ __align__(16) short Bs[BN * BK];   // [x][k] swizzled, 16KB

    // XCD-aware bijective swizzle: 2048 blocks, 8 XCDs, 256 per XCD
    int raw = blockIdx.x;
    int sb  = (raw & 7) * 256 + (raw >> 3);
    int ot = sb & 1;                 // o-tile (fastest -> pairs share B panel)
    int xt = (sb >> 1) & 255;        // x-tile
    int b  = sb >> 9;                // batch
    int o0 = ot * BM, x0 = xt * BN;

    const unsigned short* Ab = Amat + ((size_t)b * NC + o0) * KTOT;

    int t = threadIdx.x;
    int wave = t >> 6, lane = t & 63;
    int wr = wave >> 1, wc = wave & 1;
    int lrow = lane & 15, lk = lane >> 4;

    f32x4 acc[4][4];
    #pragma unroll
    for (int mi = 0; mi < 4; ++mi)
        #pragma unroll
        for (int ni = 0; ni < 4; ++ni)
            acc[mi][ni] = (f32x4){0.f, 0.f, 0.f, 0.f};

    // B staging mapping: thread t loads float4-wide (4 x's) for 8 consecutive
    // k's, then writes 4 K-contiguous ds_write_b128 (one per x).
    int xq = t & 31;                 // x-group (4 floats each)
    int kb = (t >> 5) * 8;           // k base (0..56)

    for (int it = 0; it < KTOT / BK; ++it) {
        int k0 = it * BK;
        int m  = it >> 2;                    // modality for this K-slab
        int cbase = (it & 3) * 64;           // channel base within modality
        const float* Bb = (m == 0 ? i0 : m == 1 ? i1 : m == 2 ? i2 : i3)
                          + ((size_t)b * NC + cbase) * DWH + x0;

        // ---- stage A (bf16, already K-contiguous in global) ----
        uint4 areg[4];
        #pragma unroll
        for (int i = 0; i < 4; ++i) {
            int id = i * 256 + t;            // 0..1023 = 128 rows x 8 chunks
            int r = id >> 3, q = id & 7;
            areg[i] = *(const uint4*)(Ab + (size_t)r * KTOT + k0 + q * 8);
        }
        // ---- stage B loads (fp32) ----
        float4 v[8];
        #pragma unroll
        for (int j = 0; j < 8; ++j)
            v[j] = *(const float4*)(Bb + (size_t)(kb + j) * DWH + xq * 4);

        __syncthreads();   // previous iteration's compute done -> safe to overwrite

        #pragma unroll
        for (int i = 0; i < 4; ++i) {
            int id = i * 256 + t;
            int r = id >> 3, q = id & 7;
            *(uint4*)(&As[swz(r, q)]) = areg[i];
        }
        #pragma unroll
        for (int i = 0; i < 4; ++i) {
            short8 pk;
            #pragma unroll
            for (int j = 0; j < 8; ++j)
                pk[j] = (short)f32_to_bf16(((const float*)&v[j])[i]);
            int xl = xq * 4 + i;
            *(short8*)(&Bs[swz(xl, t >> 5)]) = pk;
        }
        __syncthreads();   // staging visible

        // ---- compute: 2 K-halves of 32 ----
        #pragma unroll
        for (int kk = 0; kk < 2; ++kk) {
            int q = kk * 4 + lk;
            short8 af[4], bf[4];
            #pragma unroll
            for (int mi = 0; mi < 4; ++mi) {
                int r = wr * 64 + mi * 16 + lrow;
                af[mi] = *(const short8*)(&As[swz(r, q)]);
            }
            #pragma unroll
            for (int ni = 0; ni < 4; ++ni) {
                int x = wc * 64 + ni * 16 + lrow;
                bf[ni] = *(const short8*)(&Bs[swz(x, q)]);
            }
            #pragma unroll
            for (int mi = 0; mi < 4; ++mi)
                #pragma unroll
                for (int ni = 0; ni < 4; ++ni)
                    acc[mi][ni] = __builtin_amdgcn_mfma_f32_16x16x32_bf16(
                        af[mi], bf[ni], acc[mi][ni], 0, 0, 0);
        }
    }

    // ---- epilogue: add bias, store fp32 ----
    // C/D layout (16x16x32): col = lane&15, row = (lane>>4)*4 + reg
    const float* beff_b = beff + b * NC + o0;
    float* outb = out + ((size_t)b * NC + o0) * DWH + x0;
    #pragma unroll
    for (int mi = 0; mi < 4; ++mi) {
        #pragma unroll
        for (int r4 = 0; r4 < 4; ++r4) {
            int row = wr * 64 + mi * 16 + lk * 4 + r4;
            float bias = beff_b[row];
            float* orow = outb + (size_t)row * DWH;
            #pragma unroll
            for (int ni = 0; ni < 4; ++ni) {
                int col = wc * 64 + ni * 16 + lrow;
                orow[col] = acc[mi][ni][r4] + bias;
            }
        }
    }
}

// ---------------------------------------------------------------------------
extern "C" void kernel_launch(void* const* d_in, const int* in_sizes, int n_in,
                              void* d_out, int out_size, void* d_ws, size_t ws_size,
                              hipStream_t stream) {
    const float* m1 = (const float*)d_in[0];
    const float* m2 = (const float*)d_in[1];
    const float* m3 = (const float*)d_in[2];
    const float* m4 = (const float*)d_in[3];
    const float* Wq = (const float*)d_in[4];
    const float* bq = (const float*)d_in[5];
    const float* Wk = (const float*)d_in[6];
    const float* bk = (const float*)d_in[7];
    const float* Wc = (const float*)d_in[8];
    const float* bcv = (const float*)d_in[9];
    float* out = (float*)d_out;

    // workspace layout
    float* pooled        = (float*)d_ws;                                // 512 KB
    unsigned short* Amat = (unsigned short*)((char*)d_ws + 524288);     // 2 MB
    float* beff          = (float*)((char*)d_ws + 524288 + 2097152);    // 4 KB

    pool_kernel<<<NB * NC * 4, 256, 0, stream>>>(m1, m2, m3, m4, pooled);
    attn_kernel<<<NB * NC, 64, 0, stream>>>(pooled, Wq, bq, Wk, bk, Wc, bcv,
                                            Amat, beff);
    gemm_kernel<<<(NB) * (NC / BM) * (DWH / BN), 256, 0, stream>>>(
        m1, m2, m3, m4, Amat, beff, out);
}

// Round 2
// 264.906 us; speedup vs baseline: 1.5619x; 1.5619x over previous
//
#include <hip/hip_runtime.h>
#include <hip/hip_bf16.h>

// Problem constants
#define NB 4
#define NC 256
#define ND 32
#define WH 1024          // W*H
#define DWH 32768        // D*W*H
#define KTOT 1024        // 4 modalities * 256 channels

typedef __attribute__((ext_vector_type(8))) short short8;
typedef __attribute__((ext_vector_type(4))) float f32x4;

static __device__ __forceinline__ unsigned short f32_to_bf16(float f) {
    unsigned u = __builtin_bit_cast(unsigned, f);
    u = u + 0x7fff + ((u >> 16) & 1);   // round-to-nearest-even
    return (unsigned short)(u >> 16);
}

// ---------------------------------------------------------------------------
// Kernel 1: adaptive_avg_pool3d(x,(D,1,1)) == mean over W,H -> pooled[b][c][m][d]
// ---------------------------------------------------------------------------
__global__ __launch_bounds__(256) void pool_kernel(
    const float* __restrict__ i0, const float* __restrict__ i1,
    const float* __restrict__ i2, const float* __restrict__ i3,
    float* __restrict__ pooled)
{
    int bid = blockIdx.x;            // (b*NC + c)*4 + m
    int m   = bid & 3;
    int bc  = bid >> 2;              // b*NC + c
    const float* src = (m == 0 ? i0 : m == 1 ? i1 : m == 2 ? i2 : i3)
                       + (size_t)bc * DWH;
    int t = threadIdx.x;
    int wave = t >> 6, lane = t & 63;

    for (int d = wave; d < ND; d += 4) {
        const float4* row = (const float4*)(src + (size_t)d * WH);
        float s = 0.f;
        #pragma unroll
        for (int j = 0; j < 4; ++j) {
            float4 v = row[lane + 64 * j];
            s += v.x + v.y + v.z + v.w;
        }
        #pragma unroll
        for (int off = 32; off; off >>= 1) s += __shfl_down(s, off, 64);
        if (lane == 0) pooled[bc * 128 + m * 32 + d] = s * (1.0f / 1024.0f);
    }
}

// ---------------------------------------------------------------------------
// Kernel 2: attention weights + effective GEMM A-matrix + effective bias.
// ---------------------------------------------------------------------------
__global__ __launch_bounds__(64) void attn_kernel(
    const float* __restrict__ pooled,
    const float* __restrict__ Wq, const float* __restrict__ bq,
    const float* __restrict__ Wk, const float* __restrict__ bk,
    const float* __restrict__ Wc, const float* __restrict__ bcv,
    unsigned short* __restrict__ Amat, float* __restrict__ beff)
{
    int bc_idx = blockIdx.x;             // b*NC + c
    int lane = threadIdx.x;
    int e = lane & 31;
    const float* P = pooled + bc_idx * 128;

    float q = 0.f, kv[4] = {0.f, 0.f, 0.f, 0.f};
    for (int d = 0; d < 32; ++d) {
        float pq = P[d];
        float wq = Wq[e * 32 + d], wk = Wk[e * 32 + d];
        q += pq * wq;
        #pragma unroll
        for (int m = 0; m < 4; ++m) kv[m] += P[m * 32 + d] * wk;
    }
    q += bq[e];
    #pragma unroll
    for (int m = 0; m < 4; ++m) kv[m] += bk[e];

    float lg[4];
    #pragma unroll
    for (int m = 0; m < 4; ++m) {
        float p = q * kv[m];
        #pragma unroll
        for (int off = 16; off; off >>= 1) p += __shfl_xor(p, off, 32);
        lg[m] = p * 0.17677669529663687f;    // 1/sqrt(32)
    }
    float mx = fmaxf(fmaxf(lg[0], lg[1]), fmaxf(lg[2], lg[3]));
    float ex[4], s = 0.f;
    #pragma unroll
    for (int m = 0; m < 4; ++m) { ex[m] = __expf(lg[m] - mx); s += ex[m]; }
    float a[4];
    #pragma unroll
    for (int m = 0; m < 4; ++m) a[m] = ex[m] / s;

    int c = bc_idx & 255;
    if (lane == 0) {
        float be = 0.f;
        #pragma unroll
        for (int m = 0; m < 4; ++m) be += a[m] * bcv[m * NC + c];
        beff[bc_idx] = be;
    }
    unsigned short* Arow = Amat + (size_t)bc_idx * KTOT;
    #pragma unroll
    for (int j = 0; j < 16; ++j) {
        int k = j * 64 + lane;
        int m = k >> 8, cin = k & 255;
        float v = a[m] * Wc[(m * NC + c) * NC + cin];
        Arow[k] = f32_to_bf16(v);
    }
}

// ---------------------------------------------------------------------------
// Kernel 3: per-batch GEMM, pipelined.
//   out[b][o][x] = sum_k Amat[b][o][k]*M[b][k][x] + beff
//   Tile 128x128, BK=64. A: global_load_lds (pre-swizzled source, linear LDS
//   dest). B: reg-staged fp32->bf16 with 1-deep prefetch so HBM latency hides
//   under the MFMA phase.
// ---------------------------------------------------------------------------
#define BM 128
#define BN 128
#define BK 64

static __device__ __forceinline__ int swz(int row, int chunk) {
    // ushort units: row stride 64 ushorts (=128B), chunk = 8 ushorts (=16B)
    return row * 64 + ((chunk ^ (row & 7)) << 3);
}

__global__ __launch_bounds__(256, 3) void gemm_kernel(
    const float* __restrict__ i0, const float* __restrict__ i1,
    const float* __restrict__ i2, const float* __restrict__ i3,
    const unsigned short* __restrict__ Amat,
    const float* __restrict__ beff,
    float* __restrict__ out)
{
    __shared__ __align__(16) short As[BM * BK];   // [o][k] swizzled, 16KB
    __shared__ __align__(16) short Bs[BN * BK];   // [x][k] swizzled, 16KB

    // XCD-aware bijective swizzle: 2048 blocks, 8 XCDs, 256 per XCD
    int raw = blockIdx.x;
    int sb  = (raw & 7) * 256 + (raw >> 3);
    int ot = sb & 1;                 // o-tile (fastest -> pairs share B panel)
    int xt = (sb >> 1) & 255;        // x-tile
    int b  = sb >> 9;                // batch
    int o0 = ot * BM, x0 = xt * BN;

    const unsigned short* Ab = Amat + ((size_t)b * NC + o0) * KTOT;

    int t = threadIdx.x;
    int wave = t >> 6, lane = t & 63;
    int wr = wave >> 1, wc = wave & 1;
    int lrow = lane & 15, lk = lane >> 4;

    f32x4 acc[4][4];
    #pragma unroll
    for (int mi = 0; mi < 4; ++mi)
        #pragma unroll
        for (int ni = 0; ni < 4; ++ni)
            acc[mi][ni] = (f32x4){0.f, 0.f, 0.f, 0.f};

    // B staging mapping: thread t loads float4 (4 x's) for 8 consecutive k's.
    int xq = t & 31;                 // x-group (4 floats each)
    int kb = (t >> 5) * 8;           // k base (0..56)

    // A direct-to-LDS mapping: wave covers rows wave*32..+31; instr p covers
    // 8 rows. lane -> row offset lane>>3, slot lane&7; source chunk
    // pre-swizzled: q = (lane&7) ^ (lane>>3)  (since row&7 == lane>>3).
    int ar = wave * 32 + (lane >> 3);
    int aq = (lane & 7) ^ (lane >> 3);
    const unsigned short* asrc = Ab + (size_t)ar * KTOT + aq * 8;

    float4 v[8];
    // ---- prologue: load B for it=0 ----
    {
        const float* Bb = i0 + (size_t)b * NC * DWH + x0;   // it=0: m=0, cbase=0
        #pragma unroll
        for (int j = 0; j < 8; ++j)
            v[j] = *(const float4*)(Bb + (size_t)(kb + j) * DWH + xq * 4);
    }

    for (int it = 0; it < KTOT / BK; ++it) {
        int k0 = it * BK;

        __syncthreads();   // previous compute done -> LDS writable

        // ---- A: async direct-to-LDS (swizzled via source permutation) ----
        #pragma unroll
        for (int p = 0; p < 4; ++p)
            __builtin_amdgcn_global_load_lds(
                (const __attribute__((address_space(1))) unsigned int*)
                    (asrc + (size_t)p * 8 * KTOT + k0),
                (__attribute__((address_space(3))) unsigned int*)
                    (As + (wave * 32 + p * 8) * 64),
                16, 0, 0);

        // ---- B: convert staged regs to bf16, write swizzled ----
        #pragma unroll
        for (int i = 0; i < 4; ++i) {
            short8 pk;
            #pragma unroll
            for (int j = 0; j < 8; ++j)
                pk[j] = (short)f32_to_bf16(((const float*)&v[j])[i]);
            int xl = xq * 4 + i;
            *(short8*)(&Bs[swz(xl, t >> 5)]) = pk;
        }

        __syncthreads();   // drains global_load_lds + ds writes -> LDS ready

        // ---- prefetch B for it+1 (overlaps compute below) ----
        if (it + 1 < KTOT / BK) {
            int itn = it + 1;
            int m  = itn >> 2;
            int cbase = (itn & 3) * 64;
            const float* Bb = (m == 0 ? i0 : m == 1 ? i1 : m == 2 ? i2 : i3)
                              + ((size_t)b * NC + cbase) * DWH + x0;
            #pragma unroll
            for (int j = 0; j < 8; ++j)
                v[j] = *(const float4*)(Bb + (size_t)(kb + j) * DWH + xq * 4);
        }

        // ---- compute: 2 K-halves of 32 ----
        #pragma unroll
        for (int kk = 0; kk < 2; ++kk) {
            int q = kk * 4 + lk;
            short8 af[4], bf[4];
            #pragma unroll
            for (int mi = 0; mi < 4; ++mi) {
                int r = wr * 64 + mi * 16 + lrow;
                af[mi] = *(const short8*)(&As[swz(r, q)]);
            }
            #pragma unroll
            for (int ni = 0; ni < 4; ++ni) {
                int x = wc * 64 + ni * 16 + lrow;
                bf[ni] = *(const short8*)(&Bs[swz(x, q)]);
            }
            #pragma unroll
            for (int mi = 0; mi < 4; ++mi)
                #pragma unroll
                for (int ni = 0; ni < 4; ++ni)
                    acc[mi][ni] = __builtin_amdgcn_mfma_f32_16x16x32_bf16(
                        af[mi], bf[ni], acc[mi][ni], 0, 0, 0);
        }
    }

    // ---- epilogue: add bias, store fp32 ----
    // C/D layout (16x16x32): col = lane&15, row = (lane>>4)*4 + reg
    const float* beff_b = beff + b * NC + o0;
    float* outb = out + ((size_t)b * NC + o0) * DWH + x0;
    #pragma unroll
    for (int mi = 0; mi < 4; ++mi) {
        #pragma unroll
        for (int r4 = 0; r4 < 4; ++r4) {
            int row = wr * 64 + mi * 16 + lk * 4 + r4;
            float bias = beff_b[row];
            float* orow = outb + (size_t)row * DWH;
            #pragma unroll
            for (int ni = 0; ni < 4; ++ni) {
                int col = wc * 64 + ni * 16 + lrow;
                orow[col] = acc[mi][ni][r4] + bias;
            }
        }
    }
}

// ---------------------------------------------------------------------------
extern "C" void kernel_launch(void* const* d_in, const int* in_sizes, int n_in,
                              void* d_out, int out_size, void* d_ws, size_t ws_size,
                              hipStream_t stream) {
    const float* m1 = (const float*)d_in[0];
    const float* m2 = (const float*)d_in[1];
    const float* m3 = (const float*)d_in[2];
    const float* m4 = (const float*)d_in[3];
    const float* Wq = (const float*)d_in[4];
    const float* bq = (const float*)d_in[5];
    const float* Wk = (const float*)d_in[6];
    const float* bk = (const float*)d_in[7];
    const float* Wc = (const float*)d_in[8];
    const float* bcv = (const float*)d_in[9];
    float* out = (float*)d_out;

    float* pooled        = (float*)d_ws;                                // 512 KB
    unsigned short* Amat = (unsigned short*)((char*)d_ws + 524288);     // 2 MB
    float* beff          = (float*)((char*)d_ws + 524288 + 2097152);    // 4 KB

    pool_kernel<<<NB * NC * 4, 256, 0, stream>>>(m1, m2, m3, m4, pooled);
    attn_kernel<<<NB * NC, 64, 0, stream>>>(pooled, Wq, bq, Wk, bk, Wc, bcv,
                                            Amat, beff);
    gemm_kernel<<<(NB) * (NC / BM) * (DWH / BN), 256, 0, stream>>>(
        m1, m2, m3, m4, Amat, beff, out);
}